// Round 1
// baseline (2641.005 us; speedup 1.0000x reference)
//
#include <hip/hip_runtime.h>

// ws layout (floats)
#define WS_GX   0                       // 4096: Gx[cp][c] = alpha*sum_o wk[o][c]*wq[o][cp]
#define WS_CPV  4096                    // 4096: Cpvx[c][o] = sum_m wp[o][m]*wv[m][c]
#define WS_QB   8192                    // 64:   alpha * Wk^T bq
#define WS_BPV  8256                    // 64:   Wp bv + bp
#define WS_C2   8448                    // 4096*1536 conv2 output (flattened fc input)
#define WS_Z1   (8448 + 4096*1536)      // 4096*768 fc1 output

// ---------------- K0: tiny precompute of fused weight products ----------------
__global__ void k0_precompute(const float* __restrict__ wq, const float* __restrict__ bq,
                              const float* __restrict__ wk, const float* __restrict__ bk,
                              const float* __restrict__ wv, const float* __restrict__ bv,
                              const float* __restrict__ wp, const float* __restrict__ bp,
                              float* __restrict__ ws) {
  int idx = blockIdx.x * 256 + threadIdx.x;
  const float ALPHA = 0.125f * 1.4426950408889634f;  // C^-0.5 * log2(e), folded into scores
  if (idx < 4096) {
    int cp = idx >> 6, c = idx & 63;
    float s = 0.f;
    for (int o = 0; o < 64; ++o) s += wk[o*64 + c] * wq[o*64 + cp];
    ws[WS_GX + idx] = s * ALPHA;
  } else if (idx < 8192) {
    int i = idx - 4096; int c = i >> 6, o = i & 63;
    float s = 0.f;
    for (int m = 0; m < 64; ++m) s += wp[o*64 + m] * wv[m*64 + c];
    ws[WS_CPV + i] = s;
  } else if (idx < 8256) {
    int c = idx - 8192;
    float s = 0.f;
    for (int o = 0; o < 64; ++o) s += wk[o*64 + c] * bq[o];
    ws[WS_QB + c] = s * ALPHA;
  } else if (idx < 8320) {
    int o = idx - 8256;
    float s = bp[o];
    for (int m = 0; m < 64; ++m) s += wp[o*64 + m] * bv[m];
    ws[WS_BPV + o] = s;
  }
}

// ---------------- K1: per-sample pipeline (conv1 -> GN -> attention -> conv2) ----------------
// block = 192 threads (1 per token t = y*64+x), grid = 4096 samples.
// Hs layout: channel-major [c][196] (stride 196: conflict-free lane-consecutive writes,
// 16B-aligned (784B row) for broadcast ds_read_b128 of 4 consecutive tokens).
__launch_bounds__(192, 3)
__global__ void k1_sample(const float* __restrict__ x,
                          const float* __restrict__ w1, const float* __restrict__ b1,
                          const float* __restrict__ chw, const float* __restrict__ chb,
                          const float* __restrict__ gnw, const float* __restrict__ gnb,
                          const float* __restrict__ ch2w, const float* __restrict__ ch2b,
                          const float* __restrict__ ws, float* __restrict__ c2out) {
  __shared__ float Hs[64 * 196];
  __shared__ float redS[192];
  __shared__ float redQ[192];
  __shared__ float scS[64];
  __shared__ float shS[64];

  const int t = threadIdx.x;       // token 0..191
  const int b = blockIdx.x;        // sample
  const int y = t >> 6;            // 0..2   (wave-uniform)
  const int xx = t & 63;           // 0..63

  const float x0 = x[b*3+0], x1 = x[b*3+1], x2 = x[b*3+2];

  // h1 window values hv[dy*3+dx] = h1[y+dy-1][xx+dx-1] with zero padding.
  // h1[r][cc] = x[r]*w1[cc] + b1[cc]
  float hv[9];
  {
    #pragma unroll
    for (int dy = 0; dy < 3; ++dy) {
      int r = y + dy - 1;
      bool rv = (r >= 0) && (r < 3);
      float xr = (r == 0) ? x0 : ((r == 1) ? x1 : x2);
      #pragma unroll
      for (int dx = 0; dx < 3; ++dx) {
        int cc = xx + dx - 1;
        bool cv = (cc >= 0) && (cc < 64);
        float w1v = cv ? w1[cc] : 0.f;
        float b1v = cv ? b1[cc] : 0.f;
        hv[dy*3+dx] = rv ? fmaf(xr, w1v, cv ? b1v : 0.f) : 0.f;
      }
    }
  }

  // conv1 (1->64): A[c][t] into Hs
  for (int c = 0; c < 64; ++c) {
    float acc = chb[c];
    #pragma unroll
    for (int q = 0; q < 9; ++q) acc = fmaf(chw[c*9+q], hv[q], acc);
    Hs[c*196 + t] = acc;
  }
  __syncthreads();

  // instance-norm stats: thread t handles channel c=t&63, token segment seg=y
  {
    int c = t & 63, seg = y;
    float s = 0.f, q = 0.f;
    int base = c*196 + seg*64;
    for (int u = 0; u < 64; ++u) { float v = Hs[base + u]; s += v; q = fmaf(v, v, q); }
    redS[t] = s; redQ[t] = q;
  }
  __syncthreads();
  if (t < 64) {
    float s = redS[t] + redS[64+t] + redS[128+t];
    float q = redQ[t] + redQ[64+t] + redQ[128+t];
    float mu  = s * (1.f/192.f);
    float var = q * (1.f/192.f) - mu*mu;
    float rs  = rsqrtf(var + 1e-5f);
    float sc  = gnw[t] * rs;
    scS[t] = sc;
    shS[t] = gnb[t] - mu * sc;
  }
  __syncthreads();
  // normalize in place
  for (int c = 0; c < 64; ++c)
    Hs[c*196 + t] = fmaf(Hs[c*196 + t], scS[c], shS[c]);
  __syncthreads();

  // ---- attention ----
  const float* __restrict__ Gx  = ws + WS_GX;
  const float* __restrict__ qb  = ws + WS_QB;
  const float* __restrict__ Cpv = ws + WS_CPV;
  const float* __restrict__ bpv = ws + WS_BPV;

  // q~[c] = qb[c] + sum_cp Gx[cp][c] * h[cp][t]   (scores s[t][u] = q~ . h[.][u])
  float qt[64];
  #pragma unroll
  for (int o = 0; o < 64; ++o) qt[o] = qb[o];
  for (int cp = 0; cp < 64; ++cp) {
    float h = Hs[cp*196 + t];
    const float* g = Gx + cp*64;
    #pragma unroll
    for (int o = 0; o < 64; ++o) qt[o] = fmaf(g[o], h, qt[o]);
  }

  // online softmax + g = attn @ h  (h broadcast from LDS, 4 tokens per pass)
  float gacc[64];
  #pragma unroll
  for (int c = 0; c < 64; ++c) gacc[c] = 0.f;
  float m = -1e30f, l = 0.f;
  for (int u0 = 0; u0 < 192; u0 += 4) {
    float s0 = 0.f, s1 = 0.f, s2 = 0.f, s3 = 0.f;
    #pragma unroll
    for (int c = 0; c < 64; ++c) {
      const float4 h4 = *(const float4*)&Hs[c*196 + u0];
      float q = qt[c];
      s0 = fmaf(q, h4.x, s0); s1 = fmaf(q, h4.y, s1);
      s2 = fmaf(q, h4.z, s2); s3 = fmaf(q, h4.w, s3);
    }
    float mn = fmaxf(fmaxf(fmaxf(s0, s1), fmaxf(s2, s3)), m);
    float alpha = __builtin_exp2f(m - mn);
    float p0 = __builtin_exp2f(s0 - mn);
    float p1 = __builtin_exp2f(s1 - mn);
    float p2 = __builtin_exp2f(s2 - mn);
    float p3 = __builtin_exp2f(s3 - mn);
    l = fmaf(l, alpha, (p0 + p1) + (p2 + p3));
    m = mn;
    #pragma unroll
    for (int c = 0; c < 64; ++c) {
      const float4 h4 = *(const float4*)&Hs[c*196 + u0];
      float gg = gacc[c] * alpha;
      gg = fmaf(p0, h4.x, gg); gg = fmaf(p1, h4.y, gg);
      gg = fmaf(p2, h4.z, gg); gg = fmaf(p3, h4.w, gg);
      gacc[c] = gg;
    }
  }
  {
    float rl = 1.f / l;
    #pragma unroll
    for (int c = 0; c < 64; ++c) gacc[c] *= rl;
  }

  // p[o] = bpv[o] + sum_c Cpvx[c][o]*g[c]   (reuse qt registers for p)
  #pragma unroll
  for (int o = 0; o < 64; ++o) qt[o] = bpv[o];
  for (int c = 0; c < 64; ++c) {
    float g = gacc[c];
    const float* cp = Cpv + c*64;
    #pragma unroll
    for (int o = 0; o < 64; ++o) qt[o] = fmaf(cp[o], g, qt[o]);
  }

  __syncthreads();   // all attention reads of Hs complete before overwrite

  // residual: res[c][t] = conv1(c,t) (recomputed) + p[c]
  for (int c = 0; c < 64; ++c) {
    float acc = chb[c];
    #pragma unroll
    for (int q = 0; q < 9; ++q) acc = fmaf(chw[c*9+q], hv[q], acc);
    Hs[c*196 + t] = acc + qt[c];
  }
  __syncthreads();

  // conv2 (64->8)
  float acc2[8];
  #pragma unroll
  for (int o = 0; o < 8; ++o) acc2[o] = ch2b[o];
  for (int c = 0; c < 64; ++c) {
    float win[9];
    #pragma unroll
    for (int dy = 0; dy < 3; ++dy) {
      int r = y + dy - 1;
      bool rv = (r >= 0) && (r < 3);
      #pragma unroll
      for (int dx = 0; dx < 3; ++dx) {
        int cc = xx + dx - 1;
        bool cv = (cc >= 0) && (cc < 64);
        win[dy*3+dx] = (rv && cv) ? Hs[c*196 + r*64 + cc] : 0.f;
      }
    }
    #pragma unroll
    for (int o = 0; o < 8; ++o) {
      const float* w = ch2w + o*576 + c*9;
      float a = acc2[o];
      #pragma unroll
      for (int q = 0; q < 9; ++q) a = fmaf(w[q], win[q], a);
      acc2[o] = a;
    }
  }
  #pragma unroll
  for (int o = 0; o < 8; ++o) c2out[b*1536 + o*192 + t] = acc2[o];
}

// ---------------- K2: fc1 GEMM  z1[4096][768] = relu(c2[4096][1536] @ w2^T + b2) ----------------
// 256 threads, tile 128m x 64n x 32k, 8x4 per thread (rows strided by 16 for bank-conflict-free reads)
__launch_bounds__(256, 4)
__global__ void k2_fc1(const float* __restrict__ A, const float* __restrict__ w2,
                       const float* __restrict__ b2, float* __restrict__ z1) {
  __shared__ float As[128 * 33];
  __shared__ float Bs[32 * 68];
  const int tid = threadIdx.x;
  const int m0 = blockIdx.x * 128;
  const int n0 = blockIdx.y * 64;
  const int tm = tid & 15, tn = tid >> 4;   // tn 0..15

  float acc[8][4];
  #pragma unroll
  for (int i = 0; i < 8; ++i)
    #pragma unroll
    for (int j = 0; j < 4; ++j) acc[i][j] = 0.f;

  for (int k0 = 0; k0 < 1536; k0 += 32) {
    #pragma unroll
    for (int i = 0; i < 4; ++i) {   // stage A 128x32
      int j = tid + i*256;
      int mm = j >> 3, k4 = (j & 7) << 2;
      float4 v = *(const float4*)&A[(m0+mm)*1536 + k0 + k4];
      As[mm*33 + k4+0] = v.x; As[mm*33 + k4+1] = v.y;
      As[mm*33 + k4+2] = v.z; As[mm*33 + k4+3] = v.w;
    }
    #pragma unroll
    for (int i = 0; i < 2; ++i) {   // stage B 64x32 transposed -> Bs[k][68]
      int j = tid + i*256;
      int nn = j >> 3, k4 = (j & 7) << 2;
      float4 v = *(const float4*)&w2[(n0+nn)*1536 + k0 + k4];
      Bs[(k4+0)*68 + nn] = v.x; Bs[(k4+1)*68 + nn] = v.y;
      Bs[(k4+2)*68 + nn] = v.z; Bs[(k4+3)*68 + nn] = v.w;
    }
    __syncthreads();
    #pragma unroll
    for (int k = 0; k < 32; ++k) {
      float a[8];
      #pragma unroll
      for (int i = 0; i < 8; ++i) a[i] = As[(tm + 16*i)*33 + k];
      float4 bv = *(const float4*)&Bs[k*68 + tn*4];
      #pragma unroll
      for (int i = 0; i < 8; ++i) {
        acc[i][0] = fmaf(a[i], bv.x, acc[i][0]);
        acc[i][1] = fmaf(a[i], bv.y, acc[i][1]);
        acc[i][2] = fmaf(a[i], bv.z, acc[i][2]);
        acc[i][3] = fmaf(a[i], bv.w, acc[i][3]);
      }
    }
    __syncthreads();
  }
  float4 bb = *(const float4*)&b2[n0 + tn*4];
  #pragma unroll
  for (int i = 0; i < 8; ++i) {
    float4 r;
    r.x = fmaxf(acc[i][0] + bb.x, 0.f);
    r.y = fmaxf(acc[i][1] + bb.y, 0.f);
    r.z = fmaxf(acc[i][2] + bb.z, 0.f);
    r.w = fmaxf(acc[i][3] + bb.w, 0.f);
    *(float4*)&z1[(m0 + tm + 16*i)*768 + n0 + tn*4] = r;
  }
}

// ---------------- K3: fc2+relu+fc3  out[b] = b4 + sum_o w4[o]*relu(b3[o] + w3[o].z1[b]) ----------------
// 16 samples per block, 256 blocks
__launch_bounds__(256, 2)
__global__ void k3_fc23(const float* __restrict__ z1, const float* __restrict__ w3,
                        const float* __restrict__ b3, const float* __restrict__ w4,
                        const float* __restrict__ b4, float* __restrict__ out) {
  __shared__ float Zs[16 * 772];
  __shared__ float Ws[32 * 68];
  __shared__ float red[256];
  const int tid = threadIdx.x;
  const int m0 = blockIdx.x * 16;
  const int tm = tid & 15, tn = tid >> 4;   // tn 0..15 -> 4 fc2 outputs each

  #pragma unroll
  for (int i = 0; i < 12; ++i) {   // stage Zs 16x768
    int j = tid + i*256;
    int mm = j / 192;
    int kq = j - mm*192;
    float4 v = *(const float4*)&z1[(m0+mm)*768 + kq*4];
    *(float4*)&Zs[mm*772 + kq*4] = v;
  }

  float a0 = 0.f, a1 = 0.f, a2 = 0.f, a3 = 0.f;
  for (int k0 = 0; k0 < 768; k0 += 32) {
    __syncthreads();
    #pragma unroll
    for (int i = 0; i < 2; ++i) {  // stage Ws[32k][68] transposed from w3[n][k]
      int j = tid + i*256;
      int nn = j >> 3, k4 = (j & 7) << 2;
      float4 v = *(const float4*)&w3[nn*768 + k0 + k4];
      Ws[(k4+0)*68 + nn] = v.x; Ws[(k4+1)*68 + nn] = v.y;
      Ws[(k4+2)*68 + nn] = v.z; Ws[(k4+3)*68 + nn] = v.w;
    }
    __syncthreads();
    #pragma unroll
    for (int k = 0; k < 32; k += 4) {
      float4 z  = *(const float4*)&Zs[tm*772 + k0 + k];
      float4 w0 = *(const float4*)&Ws[(k+0)*68 + tn*4];
      float4 w1v= *(const float4*)&Ws[(k+1)*68 + tn*4];
      float4 w2v= *(const float4*)&Ws[(k+2)*68 + tn*4];
      float4 w3v= *(const float4*)&Ws[(k+3)*68 + tn*4];
      a0 = fmaf(z.x, w0.x, a0); a1 = fmaf(z.x, w0.y, a1); a2 = fmaf(z.x, w0.z, a2); a3 = fmaf(z.x, w0.w, a3);
      a0 = fmaf(z.y, w1v.x, a0); a1 = fmaf(z.y, w1v.y, a1); a2 = fmaf(z.y, w1v.z, a2); a3 = fmaf(z.y, w1v.w, a3);
      a0 = fmaf(z.z, w2v.x, a0); a1 = fmaf(z.z, w2v.y, a1); a2 = fmaf(z.z, w2v.z, a2); a3 = fmaf(z.z, w2v.w, a3);
      a0 = fmaf(z.w, w3v.x, a0); a1 = fmaf(z.w, w3v.y, a1); a2 = fmaf(z.w, w3v.z, a2); a3 = fmaf(z.w, w3v.w, a3);
    }
  }
  float4 b3v = *(const float4*)&b3[tn*4];
  float4 w4v = *(const float4*)&w4[tn*4];
  float p = fmaxf(a0 + b3v.x, 0.f) * w4v.x
          + fmaxf(a1 + b3v.y, 0.f) * w4v.y
          + fmaxf(a2 + b3v.z, 0.f) * w4v.z
          + fmaxf(a3 + b3v.w, 0.f) * w4v.w;
  red[tid] = p;
  __syncthreads();
  if (tid < 16) {
    float s = 0.f;
    #pragma unroll
    for (int i = 0; i < 16; ++i) s += red[i*16 + tid];
    out[m0 + tid] = s + b4[0];
  }
}

extern "C" void kernel_launch(void* const* d_in, const int* in_sizes, int n_in,
                              void* d_out, int out_size, void* d_ws, size_t ws_size,
                              hipStream_t stream) {
  const float* x    = (const float*)d_in[0];
  const float* w1   = (const float*)d_in[1];
  const float* b1   = (const float*)d_in[2];
  const float* chw  = (const float*)d_in[3];
  const float* chb  = (const float*)d_in[4];
  const float* gnw  = (const float*)d_in[5];
  const float* gnb  = (const float*)d_in[6];
  const float* wq   = (const float*)d_in[7];
  const float* bq   = (const float*)d_in[8];
  const float* wk   = (const float*)d_in[9];
  const float* bk   = (const float*)d_in[10];
  const float* wv   = (const float*)d_in[11];
  const float* bv   = (const float*)d_in[12];
  const float* wp   = (const float*)d_in[13];
  const float* bp   = (const float*)d_in[14];
  const float* ch2w = (const float*)d_in[15];
  const float* ch2b = (const float*)d_in[16];
  const float* w2   = (const float*)d_in[17];
  const float* b2   = (const float*)d_in[18];
  const float* w3   = (const float*)d_in[19];
  const float* b3   = (const float*)d_in[20];
  const float* w4   = (const float*)d_in[21];
  const float* b4   = (const float*)d_in[22];
  (void)bk; (void)in_sizes; (void)n_in; (void)out_size; (void)ws_size;

  float* ws = (float*)d_ws;
  float* c2 = ws + WS_C2;
  float* z1 = ws + WS_Z1;
  float* out = (float*)d_out;

  hipLaunchKernelGGL(k0_precompute, dim3(34), dim3(256), 0, stream,
                     wq, bq, wk, bk, wv, bv, wp, bp, ws);
  hipLaunchKernelGGL(k1_sample, dim3(4096), dim3(192), 0, stream,
                     x, w1, b1, chw, chb, gnw, gnb, ch2w, ch2b, ws, c2);
  hipLaunchKernelGGL(k2_fc1, dim3(32, 12), dim3(256), 0, stream, c2, w2, b2, z1);
  hipLaunchKernelGGL(k3_fc23, dim3(256), dim3(256), 0, stream, z1, w3, b3, w4, b4, out);
}